// Round 2
// baseline (64.981 us; speedup 1.0000x reference)
//
#include <hip/hip_runtime.h>

#define D4    80      // float4 per x row (D=320)
#define DIM1  10
#define DIM2  5
#define BLK   256     // 4 waves
#define CROWS 80      // t-rows computed per block (incl. +-2 halo)
#define OROWS 76      // output rows per block
#define ITERS 10      // CROWS / (rows per block-iter = 4 waves * 2 rows)

// Layout per wave: 2 rows of 32 lanes each.
//   s    = lane & 15       : K-slot (16 slots x 20 floats, interleaved float4s)
//   half = (lane >> 4) & 1 : d-half (d in [half*5, half*5+5))
//   row  = lane >> 5       : row within wave
// Each lane holds W1[half*5+dd][i*16+s] for dd,i in [0,5) -> 100 VGPR,
// loaded once per block; hot loop is pure global-load + FMA + shfl.
__global__ __launch_bounds__(BLK)
void fused_fcl_win(const float4* __restrict__ x4,
                   const float4* __restrict__ w1g,   // W1 as float4[10*80]
                   const float*  __restrict__ w2,    // [5][10]
                   const float*  __restrict__ b2,    // [5]
                   float*        __restrict__ out,
                   int N)
{
    __shared__ float t_lds[CROWS * DIM2];   // 400 floats = 1.6 KB

    const int tid  = threadIdx.x;
    const int lane = tid & 63;
    const int wave = tid >> 6;
    const int s    = lane & 15;
    const int half = (lane >> 4) & 1;
    const int slot = wave * 2 + (lane >> 5);   // row slot within iter (0..7)

    // one-time register-resident W1 slice (L2-resident, broadcast-ish)
    float4 w1r[5][5];
    {
        const float4* wp = w1g + (half * 5) * D4 + s;
        #pragma unroll
        for (int dd = 0; dd < 5; ++dd)
            #pragma unroll
            for (int i = 0; i < 5; ++i)
                w1r[dd][i] = wp[dd * D4 + i * 16];
    }

    // per-lane W2 row (lane s computes output channel j=s; clamp the rest)
    const int j = (s < DIM2) ? s : (DIM2 - 1);
    float w2r[DIM1];
    #pragma unroll
    for (int d = 0; d < DIM1; ++d) w2r[d] = w2[j * DIM1 + d];
    const float b2r = b2[j];

    const int base = (int)blockIdx.x * OROWS;   // first output row

    auto rowptr = [&](int it) -> const float4* {
        int r  = base - 2 + it * 8 + slot;
        int rc = min(max(r, 0), N - 1);         // clamp: keep load legal
        return x4 + (size_t)rc * D4 + s;
    };

    // prologue load (iter 0)
    float4 xv[5];
    {
        const float4* xp = rowptr(0);
        #pragma unroll
        for (int i = 0; i < 5; ++i) xv[i] = xp[i * 16];
    }

    for (int it = 0; it < ITERS; ++it) {
        // prefetch next iter's row (1-deep pipeline)
        float4 xn[5];
        if (it + 1 < ITERS) {
            const float4* xp = rowptr(it + 1);
            #pragma unroll
            for (int i = 0; i < 5; ++i) xn[i] = xp[i * 16];
        }

        // layer 1: 5 partial dots for this lane's d-half, reduce over 16 K-slots
        float mine[5];
        #pragma unroll
        for (int dd = 0; dd < 5; ++dd) {
            float acc = 0.f;
            #pragma unroll
            for (int i = 0; i < 5; ++i) {
                float4 a  = w1r[dd][i];
                float4 xx = xv[i];
                acc += xx.x * a.x; acc += xx.y * a.y;
                acc += xx.z * a.z; acc += xx.w * a.w;
            }
            acc += __shfl_xor(acc, 1);
            acc += __shfl_xor(acc, 2);
            acc += __shfl_xor(acc, 4);
            acc += __shfl_xor(acc, 8);
            mine[dd] = fmaxf(acc, 0.f);
        }

        // exchange d-halves (xor 16 stays within the 32-lane row group)
        float hf[10];
        #pragma unroll
        for (int dd = 0; dd < 5; ++dd) {
            float o = __shfl_xor(mine[dd], 16);
            hf[dd]     = half ? o : mine[dd];
            hf[5 + dd] = half ? mine[dd] : o;
        }

        // layer 2 (all lanes redundant; lane s<5 owns channel s)
        float acc2 = b2r;
        #pragma unroll
        for (int d = 0; d < DIM1; ++d) acc2 += hf[d] * w2r[d];
        float t5 = fmaxf(acc2, 0.f);

        int r = base - 2 + it * 8 + slot;
        if (r < 0 || r >= N) t5 = 0.f;     // zero-pad semantics of the window
        if (half == 0 && s < DIM2)
            t_lds[(it * 8 + slot) * DIM2 + s] = t5;

        #pragma unroll
        for (int i = 0; i < 5; ++i) xv[i] = xn[i];
    }
    __syncthreads();

    // window expansion: out[n, a*5+jj] = t[n+a-2, jj]; local t row = nr+a
    const int lim = min(OROWS, N - base);
    float* outb = out + (size_t)base * 25;
    for (int e = tid; e < lim * 25; e += BLK) {
        int nr = e / 25;
        int c  = e - nr * 25;
        int a  = c / 5;
        int jj = c - a * 5;
        outb[e] = t_lds[(nr + a) * DIM2 + jj];
    }
}

extern "C" void kernel_launch(void* const* d_in, const int* in_sizes, int n_in,
                              void* d_out, int out_size, void* d_ws, size_t ws_size,
                              hipStream_t stream)
{
    const float4* x4 = (const float4*)d_in[0];
    const float4* w1 = (const float4*)d_in[1];
    const float*  w2 = (const float*)d_in[2];
    const float*  b2 = (const float*)d_in[3];

    const int N = in_sizes[0] / 320;   // 200000
    float* out = (float*)d_out;

    const int grid = (N + OROWS - 1) / OROWS;   // 2632 blocks
    fused_fcl_win<<<grid, BLK, 0, stream>>>(x4, w1, w2, b2, out, N);
}